// Round 9
// baseline (3686.742 us; speedup 1.0000x reference)
//
#include <hip/hip_runtime.h>
#include <stdint.h>

// 3-layer LSTM (H=64, B=256, S=4096, DIN=1) + linear head.
// One block/batch element; 832 thr = 13 waves: 3 groups of 4 (group = layer)
// + 1 head wave. R14: R13 (no global barrier -- free-running groups with LDS
// flag sync) hardened after an ambiguous container failure:
//  - flags via __hip_atomic_load/store (RELAXED, WORKGROUP) -> guaranteed
//    ds_read/ds_write per poll (no volatile-generic-pointer codegen risk);
//  - BOUNDED spin (131072 iters): protocol bug -> loud wrong-answer with
//    counters, never a hang;
//  - data ordering via explicit s_waitcnt lgkmcnt(0) (producer: h-writes
//    drain before flag publish; consumer: flag reads drain before h reads).
// Rationale (R12c counters): tick = VALUBusy + MfmaUtil EXACTLY (812+658 of
// 1510 cyc) -- the barrier phase-locks all waves so MFMA and VALU bursts
// serialize chip-wide. Wave of group g at step s waits {self: minP[g]>=s,
// prod: minP[g-1]>=s+1, cons: minP[g+1]>=s-3}, computes, publishes P=s+1.
// h lives in a depth-4 LDS ring -> groups drift; pipes overlap (m114).
// Carried: h=A-operand row-replicated MFMA; weights as pinned MFMA B-frags;
// bias in persistent C regs; head = 2 MFMAs on its own wave, y batched 32.

#define SQ 4096
#define HH 64
#define NB 256

typedef _Float16 h2    __attribute__((ext_vector_type(2)));
typedef _Float16 f16x8 __attribute__((ext_vector_type(8)));
typedef float    f32x4 __attribute__((ext_vector_type(4)));

__device__ __forceinline__ float frcp(float x)  { return __builtin_amdgcn_rcpf(x); }
__device__ __forceinline__ float fexp2(float x) { return __builtin_amdgcn_exp2f(x); }

__device__ __forceinline__ void pin4(uint4& r) {
    asm volatile("" : "+v"(r.x), "+v"(r.y), "+v"(r.z), "+v"(r.w));
}
__device__ __forceinline__ void pinv(f32x4& r) {
    float t0 = r[0], t1 = r[1], t2 = r[2], t3 = r[3];
    asm volatile("" : "+v"(t0), "+v"(t1), "+v"(t2), "+v"(t3));
    r[0] = t0; r[1] = t1; r[2] = t2; r[3] = t3;
}

__device__ __forceinline__ uint32_t fld(const uint32_t* p) {
    return __hip_atomic_load(p, __ATOMIC_RELAXED, __HIP_MEMORY_SCOPE_WORKGROUP);
}
__device__ __forceinline__ void fst(uint32_t* p, uint32_t v) {
    __hip_atomic_store(p, v, __ATOMIC_RELAXED, __HIP_MEMORY_SCOPE_WORKGROUP);
}

// D = A(h, rows replicated) x B(weights) + C
__device__ __forceinline__ f32x4 mm(uint4 hv, uint4 wv, f32x4 c) {
    return __builtin_amdgcn_mfma_f32_16x16x32_f16(
        __builtin_bit_cast(f16x8, hv), __builtin_bit_cast(f16x8, wv), c, 0, 0, 0);
}

// ---- prep: fp32 weights -> MFMA B-fragments (packed fp16 pairs).
// Regions: grp0 [0,8192) u32 (Whh0, KT=2); grp1 [8192,24576) ([Wih1|Whh1],
// KT=4); grp2 [24576,40960) ([Wih2|Whh2], KT=4); y-frag [40960,41472):
// 2 K-tiles (h2 range), col0 = Wlin, cols 1-15 = 0.
__global__ __launch_bounds__(256)
void prep_weights(const float* __restrict__ Whh0, const float* __restrict__ Wih1,
                  const float* __restrict__ Whh1, const float* __restrict__ Wih2,
                  const float* __restrict__ Whh2, const float* __restrict__ Wlin,
                  uint32_t* __restrict__ ws)
{
    const int idx = blockIdx.x * 256 + threadIdx.x;   // 0..41471
    if (idx >= 40960) {                               // y-fragment region
        const int r  = idx - 40960;
        const int jj = r & 3;
        const int l  = (r >> 2) & 63;
        const int kk = (r >> 8) & 1;                  // 0 -> kt2, 1 -> kt3
        const int n  = l & 15;
        const int krow = ((l >> 4) << 3) + 2 * jj;
        const int ku   = 32 * kk + krow;              // h2 unit index
        h2 t;
        t[0] = (_Float16)((n == 0) ? Wlin[ku]     : 0.f);
        t[1] = (_Float16)((n == 0) ? Wlin[ku + 1] : 0.f);
        ws[idx] = __builtin_bit_cast(uint32_t, t);
        return;
    }
    int r, ktbits;
    const float *Wi = nullptr, *Wh;
    if (idx < 8192)       { r = idx;         ktbits = 1; Wh = Whh0; }
    else if (idx < 24576) { r = idx - 8192;  ktbits = 2; Wi = Wih1; Wh = Whh1; }
    else                  { r = idx - 24576; ktbits = 2; Wi = Wih2; Wh = Whh2; }
    const int jj  = r & 3;
    const int l   = (r >> 2) & 63;
    const int rem = r >> 8;
    const int kt  = rem & ((1 << ktbits) - 1);
    const int tw  = rem >> ktbits;
    const int j   = tw & 3;
    const int w   = tw >> 2;
    const int n   = l & 15;
    const int krow = ((l >> 4) << 3) + 2 * jj;
    const int orow = 64 * j + 16 * w + n;
    int kcol = 32 * kt + krow;
    const float* M;
    if (ktbits == 1)    { M = Wh; }
    else if (kcol < 64) { M = Wi; }
    else                { M = Wh; kcol -= 64; }
    h2 t;
    t[0] = (_Float16)M[orow * HH + kcol];
    t[1] = (_Float16)M[orow * HH + kcol + 1];
    ws[idx] = __builtin_bit_cast(uint32_t, t);
}

__global__ __launch_bounds__(832)
__attribute__((amdgpu_waves_per_eu(1, 4)))
void lstm3_fused(
    const float* __restrict__ x,
    const float* __restrict__ Wih0,
    const float* __restrict__ bih0, const float* __restrict__ bhh0,
    const float* __restrict__ bih1, const float* __restrict__ bhh1,
    const float* __restrict__ bih2, const float* __restrict__ bhh2,
    const float* __restrict__ blin,
    const uint32_t* __restrict__ wpk,
    float* __restrict__ out)
{
    const int b    = blockIdx.x;
    const int tid  = threadIdx.x;
    const int wid  = tid >> 6;         // 0..12
    const int l    = tid & 63;
    const int n    = l & 15;
    const int q    = l >> 4;           // 16-lane sub-group (A k-slice)
    const bool is_head = (wid == 12);
    const int grp  = wid >> 2;         // 0,1,2 (3 for head, unused)
    const int w    = wid & 3;
    const int unit = 16 * w + n;

    __shared__ __align__(16) float xrow[SQ];
    __shared__ __align__(16) uint4 hb[4][3][8];    // [slot][layer][64 fp16]
    __shared__ __align__(16) float ystage[32];
    __shared__ uint32_t pflags[16];                // [g*4+w]; 12=head,13-15=INF

    for (int i = tid; i < SQ; i += 832) xrow[i] = x[b * SQ + i];
    if (tid < 96) ((uint4*)hb)[tid] = make_uint4(0, 0, 0, 0);
    if (tid < 16) pflags[tid] = (tid > 12) ? 0x7fffffffu : 0u;

    auto min4 = [&](int base) -> int {
        uint32_t a  = fld(&pflags[base]);
        uint32_t b1 = fld(&pflags[base + 1]);
        uint32_t c  = fld(&pflags[base + 2]);
        uint32_t d  = fld(&pflags[base + 3]);
        uint32_t m0 = a < b1 ? a : b1;
        uint32_t m1 = c < d ? c : d;
        return (int)(m0 < m1 ? m0 : m1);
    };

    // ---- weights / constants (per wave role) ----
    uint4 w00 = {}, w01 = {}, w10 = {}, w11 = {}, w20 = {}, w21 = {}, w30 = {}, w31 = {};
    uint4 w02 = {}, w03 = {}, w12 = {}, w13 = {}, w22 = {}, w23 = {}, w32 = {}, w33 = {};
    uint4 wy2 = {}, wy3 = {};
    f32x4 cb0 = {}, cb1 = {}, cb2 = {}, cb3 = {}, cy = {};
    float wx0 = 0.f, wx1 = 0.f, wx2 = 0.f, wx3 = 0.f;

    if (is_head) {
        wy2 = *reinterpret_cast<const uint4*>(wpk + 40960 + (0 * 64 + l) * 4);
        wy3 = *reinterpret_cast<const uint4*>(wpk + 40960 + (1 * 64 + l) * 4);
        pin4(wy2); pin4(wy3);
        const float bv = blin[0];
        cy = f32x4{bv, bv, bv, bv};
        pinv(cy);
    } else {
        const int gbase = (grp == 0) ? 0 : (grp == 1) ? 8192 : 24576;
        const int KT    = (grp == 0) ? 2 : 4;
        const uint32_t* wbp = wpk + gbase;
        auto fr = [&](int j_, int kt_) {
            return *reinterpret_cast<const uint4*>(
                wbp + (((w * 4 + j_) * KT + kt_) * 64 + l) * 4);
        };
        w00 = fr(0, 0); w01 = fr(0, 1); w10 = fr(1, 0); w11 = fr(1, 1);
        w20 = fr(2, 0); w21 = fr(2, 1); w30 = fr(3, 0); w31 = fr(3, 1);
        pin4(w00); pin4(w01); pin4(w10); pin4(w11);
        pin4(w20); pin4(w21); pin4(w30); pin4(w31);
        if (grp != 0) {
            w02 = fr(0, 2); w03 = fr(0, 3); w12 = fr(1, 2); w13 = fr(1, 3);
            w22 = fr(2, 2); w23 = fr(2, 3); w32 = fr(3, 2); w33 = fr(3, 3);
            pin4(w02); pin4(w03); pin4(w12); pin4(w13);
            pin4(w22); pin4(w23); pin4(w32); pin4(w33);
        }
        const float* bi = (grp == 0) ? bih0 : (grp == 1) ? bih1 : bih2;
        const float* bh = (grp == 0) ? bhh0 : (grp == 1) ? bhh1 : bhh2;
        const float bs0 = bi[unit]       + bh[unit];
        const float bs1 = bi[64 + unit]  + bh[64 + unit];
        const float bs2 = bi[128 + unit] + bh[128 + unit];
        const float bs3 = bi[192 + unit] + bh[192 + unit];
        cb0 = f32x4{bs0, bs0, bs0, bs0};  pinv(cb0);
        cb1 = f32x4{bs1, bs1, bs1, bs1};  pinv(cb1);
        cb2 = f32x4{bs2, bs2, bs2, bs2};  pinv(cb2);
        cb3 = f32x4{bs3, bs3, bs3, bs3};  pinv(cb3);
        if (grp == 0) {
            wx0 = Wih0[unit];       wx1 = Wih0[64 + unit];
            wx2 = Wih0[128 + unit]; wx3 = Wih0[192 + unit];
        }
    }

    __syncthreads();

    if (is_head) {
        // ---- head wave: y(s) = Wlin . h2(s) + blin, consumer of P[2] ----
        for (int s = 0; s < SQ; ++s) {
            for (int gu = 0; gu < 131072; ++gu) {
                if (min4(8) >= s + 1) break;          // all grp2 done step s
            }
            asm volatile("s_waitcnt lgkmcnt(0)" ::: "memory");
            const uint4* py = &hb[s & 3][2][q];
            const uint4 y0 = py[0], y1 = py[4];
            f32x4 d4 = mm(y0, wy2, cy);
            d4 = mm(y1, wy3, d4);
            if (l == 0) ystage[s & 31] = d4[0];
            // drain hb reads (and ystage write) before releasing the slot
            asm volatile("s_waitcnt lgkmcnt(0)" ::: "memory");
            if (l == 0) fst(&pflags[12], (uint32_t)(s + 1));
            if ((s & 31) == 31) {
                const float yv = ystage[l & 31];
                if (l < 32) out[b * SQ + (s - 31) + l] = yv;
            }
        }
        return;
    }

    // ---- group wave main loop ----
    const int la    = (grp == 2) ? 1 : 0;      // input-h layer (A side)
    const int selfb = grp * 4;
    const int prodb = (grp - 1) * 4;
    const int consb = (grp + 1) * 4;           // grp2 -> 12 (head + INF pad)
    float cc = 0.f;

    for (int s = 0; s < SQ; ++s) {
        // ---- poll: self h(s-1) complete, input h(s) ready, slot s&3 free --
        for (int gu = 0; gu < 131072; ++gu) {
            bool ok = (min4(selfb) >= s);
            if (grp != 0) ok = ok && (min4(prodb) >= s + 1);
            ok = ok && (min4(consb) >= s - 3);
            if (ok) break;
        }
        asm volatile("s_waitcnt lgkmcnt(0)" ::: "memory");

        const int sa = s & 3, sb = (s + 3) & 3;
        // A side: grp0 reads own h(s-1); grp1/2 read input-layer h(s)
        const uint4* pa = &hb[(grp == 0) ? sb : sa][la][q];
        const uint4 a0 = pa[0], a1 = pa[4];
        f32x4 d0 = mm(a0, w00, cb0);
        f32x4 d1 = mm(a0, w10, cb1);
        f32x4 d2 = mm(a0, w20, cb2);
        f32x4 d3 = mm(a0, w30, cb3);
        d0 = mm(a1, w01, d0);  d1 = mm(a1, w11, d1);
        d2 = mm(a1, w21, d2);  d3 = mm(a1, w31, d3);
        if (grp != 0) {
            const uint4* pbp = &hb[sb][grp][q];     // own h(s-1)
            const uint4 c0 = pbp[0], c1 = pbp[4];
            d0 = mm(c0, w02, d0);  d1 = mm(c0, w12, d1);
            d2 = mm(c0, w22, d2);  d3 = mm(c0, w32, d3);
            d0 = mm(c1, w03, d0);  d1 = mm(c1, w13, d1);
            d2 = mm(c1, w23, d2);  d3 = mm(c1, w33, d3);
        }

        // ---- activation (all 64 lanes redundant; D rows replicated) ----
        float gi = d0[0], gf = d1[0], gg = d2[0], go = d3[0];
        if (grp == 0) {
            const float xT = xrow[s];
            gi += wx0 * xT; gf += wx1 * xT;
            gg += wx2 * xT; go += wx3 * xT;
        }
        const float i_ = frcp(1.f + fexp2(gi * -1.44269504f));
        const float f_ = frcp(1.f + fexp2(gf * -1.44269504f));
        const float o_ = frcp(1.f + fexp2(go * -1.44269504f));
        const float tg = 2.f * frcp(1.f + fexp2(gg * -2.88539008f)) - 1.f;
        cc = f_ * cc + i_ * tg;
        const float tc = fminf(fmaxf(cc, -15.f), 15.f);
        const float e  = fexp2(tc * -2.88539008f);
        const float h  = o_ * ((1.f - e) * frcp(1.f + e));
        if (l < 16) {
            *((_Float16*)&hb[sa][grp][0] + unit) = (_Float16)h;
            if (s == SQ - 1) {
                out[NB * SQ + grp * NB * HH + b * HH + unit] = h;
                out[NB * SQ + 3 * NB * HH + grp * NB * HH + b * HH + unit] = cc;
            }
        }
        // publish: h-writes (and input reads) drained, then P = s+1
        asm volatile("s_waitcnt lgkmcnt(0)" ::: "memory");
        if (l == 0) fst(&pflags[selfb + w], (uint32_t)(s + 1));
    }
}

extern "C" void kernel_launch(void* const* d_in, const int* in_sizes, int n_in,
                              void* d_out, int out_size, void* d_ws, size_t ws_size,
                              hipStream_t stream) {
    const float* x    = (const float*)d_in[0];
    const float* Wih0 = (const float*)d_in[1];
    const float* Whh0 = (const float*)d_in[2];
    const float* bih0 = (const float*)d_in[3];
    const float* bhh0 = (const float*)d_in[4];
    const float* Wih1 = (const float*)d_in[5];
    const float* Whh1 = (const float*)d_in[6];
    const float* bih1 = (const float*)d_in[7];
    const float* bhh1 = (const float*)d_in[8];
    const float* Wih2 = (const float*)d_in[9];
    const float* Whh2 = (const float*)d_in[10];
    const float* bih2 = (const float*)d_in[11];
    const float* bhh2 = (const float*)d_in[12];
    const float* Wlin = (const float*)d_in[13];
    const float* blin = (const float*)d_in[14];
    float* out = (float*)d_out;

    uint32_t* wpk = (uint32_t*)d_ws;   // 41472 u32 = 162 KiB < ws_size
    prep_weights<<<162, 256, 0, stream>>>(Whh0, Wih1, Whh1, Wih2, Whh2, Wlin, wpk);
    lstm3_fused<<<NB, 832, 0, stream>>>(x, Wih0, bih0, bhh0,
                                        bih1, bhh1, bih2, bhh2,
                                        blin, wpk, out);
}